// Round 3
// baseline (225.259 us; speedup 1.0000x reference)
//
#include <hip/hip_runtime.h>
#include <hip/hip_bf16.h>

// Problem constants
#define NB   32      // batch
#define NC   24      // image channels
#define ND   12      // spatial
#define NN   144     // ND*ND objects
#define QD   11
#define GH   256
#define FOUT 10

typedef unsigned short u16;
typedef __attribute__((ext_vector_type(8))) short bf16x8;
typedef __attribute__((ext_vector_type(4))) float f32x4;

// Workspace layout:
//   Lq  f32 [32][144][256]  float-off 0         (= L + q@Wg1_q + bg1 folded in)
//   R   f32 [32][144][256]  float-off 1179648
//   S   f32 [32][256]       float-off 2359296
//   Bswz u16 [128][64][8]   u16-off  4734976    (MFMA B-fragment order)
// total ~9.16 MB
#define LQ_OFF  0
#define R_OFF   1179648
#define S_OFF   2359296
#define BS_U16  4734976

__device__ inline u16 f2b(float f) {
  __hip_bfloat16 h = __float2bfloat16(f);
  return *reinterpret_cast<u16*>(&h);
}

// ---------------------------------------------------------------------------
// Fused prep:
//  blocks [0, 9216): per-object projections.
//    which==0 -> Lq[b,p,:] = img·Wg1_left + coords + q·Wg1_q + bg1   (f32)
//    which==1 -> R [b,p,:] = img·Wg1_right + coords                  (f32)
//  blocks [9216, 9472): Wg2 -> bf16 B-fragment swizzle; also zero S.
//    frag fid = kt*16+nt; elem (l,e): k = kt*32+(l>>4)*8+e, n = nt*16+(l&15)
// ---------------------------------------------------------------------------
__global__ __launch_bounds__(256) void prep(const float* __restrict__ image,
                                            const float* __restrict__ question,
                                            const float* __restrict__ Wg1,
                                            const float* __restrict__ bg1,
                                            const float* __restrict__ Wg2,
                                            float* __restrict__ Lq,
                                            float* __restrict__ R,
                                            float* __restrict__ S,
                                            u16* __restrict__ Bswz) {
  int blk = blockIdx.x;
  int h   = threadIdx.x;
  if (blk < 2 * NB * NN) {
    int p     = blk % NN;
    int rest2 = blk / NN;
    int b     = rest2 & (NB - 1);
    int which = rest2 >> 5;
    const float* Wrow = Wg1 + which * (NC + 2) * GH;
    const float* img  = image + b * (NC * NN) + p;
    float acc = 0.f;
#pragma unroll
    for (int c = 0; c < NC; ++c) acc += img[c * NN] * Wrow[c * GH + h];
    int i = p / ND, j = p - i * ND;
    const float inv = 1.0f / (ND - 1);
    acc += (j * inv) * Wrow[24 * GH + h];
    acc += (i * inv) * Wrow[25 * GH + h];
    if (which == 0) {
      acc += bg1[h];
#pragma unroll
      for (int tq = 0; tq < QD; ++tq)
        acc += question[b * QD + tq] * Wg1[(2 * (NC + 2) + tq) * GH + h];
      Lq[(b * NN + p) * GH + h] = acc;
    } else {
      R[(b * NN + p) * GH + h] = acc;
    }
  } else {
    int tid = (blk - 2 * NB * NN) * 256 + h;   // 0..65535
    int e   = tid & 7;
    int l   = (tid >> 3) & 63;
    int fid = tid >> 9;
    int kt  = fid >> 4, nt = fid & 15;
    int k = kt * 32 + ((l >> 4) << 3) + e;
    int n = (nt << 4) + (l & 15);
    Bswz[tid] = f2b(Wg2[k * GH + n]);
    if (tid < NB * GH) S[tid] = 0.f;
  }
}

// ---------------------------------------------------------------------------
// MFMA pair GEMM. Block = 256 thr (4 waves), tile = 64 pairs x 256 cols.
// A[p,k] = relu(Lq[i,k] + R[j,k]) built on the fly (f32 add+max, cvt bf16)
// into a double-buffered LDS fragment buffer (1 barrier per K-step).
// Per K-step(32) per wave: 4 ds_read_b128 (A) + 4 dwordx4 (B) + 16 MFMA.
// Epilogue: +bg2, relu, row-sum, shfl-reduce, atomicAdd into S[b,:].
// Grid: (324 m-tiles, 32 batches).
// ---------------------------------------------------------------------------
__global__ __launch_bounds__(256) void pair_gemm(const float* __restrict__ Lq,
                                                 const float* __restrict__ R,
                                                 const u16* __restrict__ Bswz,
                                                 const float* __restrict__ bg2,
                                                 float* __restrict__ S) {
  const int mtile = blockIdx.x;
  const int b     = blockIdx.y;
  const int p0    = mtile * 64;
  const int t     = threadIdx.x;
  const int w     = t >> 6;
  const int l     = t & 63;

  __shared__ __align__(16) u16 As[2][2048];   // 2 bufs x 4 frags x 64 lanes x 8

  const int row   = (w << 4) | (l & 15);
  const int p     = p0 + row;
  const int i     = p / NN;
  const int j     = p - i * NN;
  const int klane = (l >> 4) << 3;             // 0,8,16,24
  const float* Lrow = Lq + (b * NN + i) * GH + klane;   // near-uniform per 16 lanes
  const float* Rrow = R + (b * NN + j) * GH + klane;
  const u16*   Bl   = Bswz + l * 8;

  f32x4 acc[4][4] = {};

  // prologue: build k-step 0 into buffer 0
  {
    float lv[8], rv[8];
    *(float4*)&lv[0] = *(const float4*)(Lrow);
    *(float4*)&lv[4] = *(const float4*)(Lrow + 4);
    *(float4*)&rv[0] = *(const float4*)(Rrow);
    *(float4*)&rv[4] = *(const float4*)(Rrow + 4);
    u16 o[8];
#pragma unroll
    for (int e = 0; e < 8; ++e) {
      float v = lv[e] + rv[e];
      o[e] = f2b(v > 0.f ? v : 0.f);
    }
    *(bf16x8*)&As[0][((w << 6) | l) << 3] = *(bf16x8*)o;
  }
  __syncthreads();

  for (int kt = 0; kt < 8; ++kt) {
    // issue next build's global loads early (hide L2 latency under MFMA)
    float lv[8], rv[8];
    if (kt < 7) {
      const float* lp = Lrow + (kt + 1) * 32;
      const float* rp = Rrow + (kt + 1) * 32;
      *(float4*)&lv[0] = *(const float4*)lp;
      *(float4*)&lv[4] = *(const float4*)(lp + 4);
      *(float4*)&rv[0] = *(const float4*)rp;
      *(float4*)&rv[4] = *(const float4*)(rp + 4);
    }
    // A fragments from current LDS buffer
    const u16* curA = &As[kt & 1][0];
    bf16x8 af[4];
#pragma unroll
    for (int mf = 0; mf < 4; ++mf)
      af[mf] = *(const bf16x8*)&curA[(mf << 9) | (l << 3)];
    // B fragments (L2-resident, coalesced 1KB/wave)
    bf16x8 bfr[4];
#pragma unroll
    for (int nt = 0; nt < 4; ++nt) {
      int fid = (kt << 4) | (w << 2) | nt;
      bfr[nt] = *(const bf16x8*)(Bl + ((size_t)fid << 9));
    }
#pragma unroll
    for (int mf = 0; mf < 4; ++mf)
#pragma unroll
      for (int nt = 0; nt < 4; ++nt)
        acc[mf][nt] = __builtin_amdgcn_mfma_f32_16x16x32_bf16(
            af[mf], bfr[nt], acc[mf][nt], 0, 0, 0);
    // finish next build: add+relu+cvt, write other LDS buffer
    if (kt < 7) {
      u16 o[8];
#pragma unroll
      for (int e = 0; e < 8; ++e) {
        float v = lv[e] + rv[e];
        o[e] = f2b(v > 0.f ? v : 0.f);
      }
      *(bf16x8*)&As[(kt + 1) & 1][((w << 6) | l) << 3] = *(bf16x8*)o;
    }
    __syncthreads();
  }

  // Epilogue: C/D layout col = l&15, row = (l>>4)*4 + reg.
  float* Sb = S + b * GH;
#pragma unroll
  for (int nt = 0; nt < 4; ++nt) {
    int n = (w << 6) + (nt << 4) + (l & 15);
    float bgv = bg2[n];
    float s = 0.f;
#pragma unroll
    for (int mf = 0; mf < 4; ++mf)
#pragma unroll
      for (int r = 0; r < 4; ++r) {
        float v = acc[mf][nt][r] + bgv;
        s += v > 0.f ? v : 0.f;
      }
    s += __shfl_xor(s, 16, 64);
    s += __shfl_xor(s, 32, 64);
    if ((l >> 4) == 0) atomicAdd(&Sb[n], s);
  }
}

// ---------------------------------------------------------------------------
// Final f-MLP: out = relu(S@Wf1+bf1)@Wf2+bf2. One block per batch.
// ---------------------------------------------------------------------------
__global__ __launch_bounds__(256) void final_mlp(const float* __restrict__ S,
                                                 const float* __restrict__ Wf1,
                                                 const float* __restrict__ bf1,
                                                 const float* __restrict__ Wf2,
                                                 const float* __restrict__ bf2,
                                                 float* __restrict__ out) {
  __shared__ float sS[GH];
  __shared__ float oS[GH];
  int b = blockIdx.x, h = threadIdx.x;
  sS[h] = S[b * GH + h];
  __syncthreads();
  float acc = bf1[h];
#pragma unroll 8
  for (int k = 0; k < GH; ++k) acc += sS[k] * Wf1[k * GH + h];
  oS[h] = acc > 0.f ? acc : 0.f;
  __syncthreads();
  if (h < FOUT) {
    float o = bf2[h];
#pragma unroll 8
    for (int k = 0; k < GH; ++k) o += oS[k] * Wf2[k * FOUT + h];
    out[b * FOUT + h] = o;
  }
}

extern "C" void kernel_launch(void* const* d_in, const int* in_sizes, int n_in,
                              void* d_out, int out_size, void* d_ws, size_t ws_size,
                              hipStream_t stream) {
  const float* image    = (const float*)d_in[0];
  const float* question = (const float*)d_in[1];
  const float* Wg1      = (const float*)d_in[2];
  const float* bg1      = (const float*)d_in[3];
  const float* Wg2      = (const float*)d_in[4];
  const float* bg2      = (const float*)d_in[5];
  const float* Wf1      = (const float*)d_in[6];
  const float* bf1      = (const float*)d_in[7];
  const float* Wf2      = (const float*)d_in[8];
  const float* bf2      = (const float*)d_in[9];
  float* out = (float*)d_out;

  float* wsf  = (float*)d_ws;
  float* Lqp  = wsf + LQ_OFF;
  float* Rp   = wsf + R_OFF;
  float* Sp   = wsf + S_OFF;
  u16*   Bswz = (u16*)d_ws + BS_U16;

  prep<<<2 * NB * NN + 256, 256, 0, stream>>>(image, question, Wg1, bg1, Wg2,
                                              Lqp, Rp, Sp, Bswz);
  pair_gemm<<<dim3(NN * NN / 64, NB), 256, 0, stream>>>(Lqp, Rp, Bswz, bg2, Sp);
  final_mlp<<<NB, 256, 0, stream>>>(Sp, Wf1, bf1, Wf2, bf2, out);
}

// Round 4
// 155.079 us; speedup vs baseline: 1.4525x; 1.4525x over previous
//
#include <hip/hip_runtime.h>
#include <hip/hip_bf16.h>

// Problem constants
#define NB   32      // batch
#define NC   24      // image channels
#define ND   12      // spatial
#define NN   144     // ND*ND objects
#define QD   11
#define GH   256
#define FOUT 10
#define MT   324     // m-tiles per batch (20736 pairs / 64)

typedef unsigned short u16;
typedef __attribute__((ext_vector_type(8))) short bf16x8;
typedef __attribute__((ext_vector_type(4))) float f32x4;

// Workspace layout:
//   Lq  f32 [32][144][256]  float-off 0         (= L + q@Wg1_q + bg1 folded in)
//   R   f32 [32][144][256]  float-off 1179648
//   S   f32 [32][256]       float-off 2359296
//   Bswz u16 [128][64][8]   u16-off  4734976    (MFMA B-fragment order)
#define LQ_OFF  0
#define R_OFF   1179648
#define S_OFF   2359296
#define BS_U16  4734976

__device__ inline u16 f2b(float f) {
  __hip_bfloat16 h = __float2bfloat16(f);
  return *reinterpret_cast<u16*>(&h);
}

// ---------------------------------------------------------------------------
// Fused prep (unchanged from round 3):
//  blocks [0, 9216): per-object projections (Lq folds q-term + bg1).
//  blocks [9216, 9472): Wg2 -> bf16 B-fragment swizzle; zero S.
// ---------------------------------------------------------------------------
__global__ __launch_bounds__(256) void prep(const float* __restrict__ image,
                                            const float* __restrict__ question,
                                            const float* __restrict__ Wg1,
                                            const float* __restrict__ bg1,
                                            const float* __restrict__ Wg2,
                                            float* __restrict__ Lq,
                                            float* __restrict__ R,
                                            float* __restrict__ S,
                                            u16* __restrict__ Bswz) {
  int blk = blockIdx.x;
  int h   = threadIdx.x;
  if (blk < 2 * NB * NN) {
    int p     = blk % NN;
    int rest2 = blk / NN;
    int b     = rest2 & (NB - 1);
    int which = rest2 >> 5;
    const float* Wrow = Wg1 + which * (NC + 2) * GH;
    const float* img  = image + b * (NC * NN) + p;
    float acc = 0.f;
#pragma unroll
    for (int c = 0; c < NC; ++c) acc += img[c * NN] * Wrow[c * GH + h];
    int i = p / ND, j = p - i * ND;
    const float inv = 1.0f / (ND - 1);
    acc += (j * inv) * Wrow[24 * GH + h];
    acc += (i * inv) * Wrow[25 * GH + h];
    if (which == 0) {
      acc += bg1[h];
#pragma unroll
      for (int tq = 0; tq < QD; ++tq)
        acc += question[b * QD + tq] * Wg1[(2 * (NC + 2) + tq) * GH + h];
      Lq[(b * NN + p) * GH + h] = acc;
    } else {
      R[(b * NN + p) * GH + h] = acc;
    }
  } else {
    int tid = (blk - 2 * NB * NN) * 256 + h;   // 0..65535
    int e   = tid & 7;
    int l   = (tid >> 3) & 63;
    int fid = tid >> 9;
    int kt  = fid >> 4, nt = fid & 15;
    int k = kt * 32 + ((l >> 4) << 3) + e;
    int n = (nt << 4) + (l & 15);
    Bswz[tid] = f2b(Wg2[k * GH + n]);
    if (tid < NB * GH) S[tid] = 0.f;
  }
}

// ---------------------------------------------------------------------------
// MFMA pair GEMM v4. Block = 256 thr (4 waves), tile = 64 pairs x 256 cols.
// XCD-pinned 1-D grid: xcd = bid&7 owns batches [4*xcd, 4*xcd+4) so each
// XCD's L2 holds its 4 batches' Lq/R (~1.2 MB) + Bswz (128 KB).
// Build: thread t -> row t>>2, k-octet t&3: R reads in 128B-contiguous runs
// of 4 lanes; add broadcast Lq row, relu, cvt; ds_write_b128 into
// XOR-swizzled fragment LDS (double-buffered, 1 barrier per K-step).
// MFMA: per wave 4 A-frags (ds_read_b128) x 4 B-frags (global, L2) -> 16 MFMA.
// Epilogue: +bg2, relu, row-sum, shfl-reduce, atomicAdd into S[b,:].
// ---------------------------------------------------------------------------
__global__ __launch_bounds__(256) void pair_gemm(const float* __restrict__ Lq,
                                                 const float* __restrict__ R,
                                                 const u16* __restrict__ Bswz,
                                                 const float* __restrict__ bg2,
                                                 float* __restrict__ S) {
  const int bid   = blockIdx.x;
  const int xcd   = bid & 7;
  const int g     = bid >> 3;            // 0..1295
  const int b     = xcd * 4 + (g / MT);  // batch
  const int mtile = g % MT;
  const int p0    = mtile * 64;
  const int t     = threadIdx.x;
  const int w     = t >> 6;
  const int l     = t & 63;

  __shared__ __align__(16) u16 As[2][2048];   // [buf][addr16*8]

  // builder role: row = t>>2 (0..63), k-octet c = t&3
  const int brow = t >> 2;
  const int c    = t & 3;
  const int p    = p0 + brow;
  const int i    = p / NN;
  const int j    = p - i * NN;
  const float* Lrow = Lq + (b * NN + i) * GH + c * 8;
  const float* Rrow = R + (b * NN + j) * GH + c * 8;
  // swizzled fragment store address (16B units)
  const int wa16 = ((brow >> 4) << 6) + ((brow & 15) << 2) + (c ^ ((brow >> 2) & 3));
  // swizzled fragment read address (16B units, + mf*64)
  const int ra16 = ((l & 15) << 2) + ((l >> 4) ^ ((l >> 2) & 3));
  const u16* Bl = Bswz + l * 8;

  f32x4 acc[4][4] = {};

  // prologue: issue k-step 0 loads
  float4 lA = *(const float4*)(Lrow);
  float4 lB = *(const float4*)(Lrow + 4);
  float4 rA = *(const float4*)(Rrow);
  float4 rB = *(const float4*)(Rrow + 4);

  for (int kt = 0; kt < 8; ++kt) {
    // build this k-step's fragment from prefetched regs
    {
      float lv[8], rv[8];
      *(float4*)&lv[0] = lA; *(float4*)&lv[4] = lB;
      *(float4*)&rv[0] = rA; *(float4*)&rv[4] = rB;
      u16 o[8];
#pragma unroll
      for (int e = 0; e < 8; ++e) {
        float v = lv[e] + rv[e];
        o[e] = f2b(v > 0.f ? v : 0.f);
      }
      *(bf16x8*)&As[kt & 1][wa16 * 8] = *(bf16x8*)o;
    }
    // issue next k-step's loads (latency hides under barrier+MFMA)
    if (kt < 7) {
      const float* lp = Lrow + (kt + 1) * 32;
      const float* rp = Rrow + (kt + 1) * 32;
      lA = *(const float4*)lp;
      lB = *(const float4*)(lp + 4);
      rA = *(const float4*)rp;
      rB = *(const float4*)(rp + 4);
    }
    __syncthreads();

    const u16* curA = As[kt & 1];
    bf16x8 af[4];
#pragma unroll
    for (int mf = 0; mf < 4; ++mf)
      af[mf] = *(const bf16x8*)&curA[(mf * 64 + ra16) * 8];
    bf16x8 bfr[4];
#pragma unroll
    for (int nt = 0; nt < 4; ++nt) {
      int fid = (kt << 4) | (w << 2) | nt;
      bfr[nt] = *(const bf16x8*)(Bl + ((size_t)fid << 9));
    }
#pragma unroll
    for (int mf = 0; mf < 4; ++mf)
#pragma unroll
      for (int nt = 0; nt < 4; ++nt)
        acc[mf][nt] = __builtin_amdgcn_mfma_f32_16x16x32_bf16(
            af[mf], bfr[nt], acc[mf][nt], 0, 0, 0);
  }

  // Epilogue: C/D layout col = l&15, row = (l>>4)*4 + reg.
  float* Sb = S + b * GH;
#pragma unroll
  for (int nt = 0; nt < 4; ++nt) {
    int n = (w << 6) + (nt << 4) + (l & 15);
    float bgv = bg2[n];
    float s = 0.f;
#pragma unroll
    for (int mf = 0; mf < 4; ++mf)
#pragma unroll
      for (int r = 0; r < 4; ++r) {
        float v = acc[mf][nt][r] + bgv;
        s += v > 0.f ? v : 0.f;
      }
    s += __shfl_xor(s, 16, 64);
    s += __shfl_xor(s, 32, 64);
    if ((l >> 4) == 0) atomicAdd(&Sb[n], s);
  }
}

// ---------------------------------------------------------------------------
// Final f-MLP: out = relu(S@Wf1+bf1)@Wf2+bf2. One block per batch.
// ---------------------------------------------------------------------------
__global__ __launch_bounds__(256) void final_mlp(const float* __restrict__ S,
                                                 const float* __restrict__ Wf1,
                                                 const float* __restrict__ bf1,
                                                 const float* __restrict__ Wf2,
                                                 const float* __restrict__ bf2,
                                                 float* __restrict__ out) {
  __shared__ float sS[GH];
  __shared__ float oS[GH];
  int b = blockIdx.x, h = threadIdx.x;
  sS[h] = S[b * GH + h];
  __syncthreads();
  float acc = bf1[h];
#pragma unroll 8
  for (int k = 0; k < GH; ++k) acc += sS[k] * Wf1[k * GH + h];
  oS[h] = acc > 0.f ? acc : 0.f;
  __syncthreads();
  if (h < FOUT) {
    float o = bf2[h];
#pragma unroll 8
    for (int k = 0; k < GH; ++k) o += oS[k] * Wf2[k * FOUT + h];
    out[b * FOUT + h] = o;
  }
}

extern "C" void kernel_launch(void* const* d_in, const int* in_sizes, int n_in,
                              void* d_out, int out_size, void* d_ws, size_t ws_size,
                              hipStream_t stream) {
  const float* image    = (const float*)d_in[0];
  const float* question = (const float*)d_in[1];
  const float* Wg1      = (const float*)d_in[2];
  const float* bg1      = (const float*)d_in[3];
  const float* Wg2      = (const float*)d_in[4];
  const float* bg2      = (const float*)d_in[5];
  const float* Wf1      = (const float*)d_in[6];
  const float* bf1      = (const float*)d_in[7];
  const float* Wf2      = (const float*)d_in[8];
  const float* bf2      = (const float*)d_in[9];
  float* out = (float*)d_out;

  float* wsf  = (float*)d_ws;
  float* Lqp  = wsf + LQ_OFF;
  float* Rp   = wsf + R_OFF;
  float* Sp   = wsf + S_OFF;
  u16*   Bswz = (u16*)d_ws + BS_U16;

  prep<<<2 * NB * NN + 256, 256, 0, stream>>>(image, question, Wg1, bg1, Wg2,
                                              Lqp, Rp, Sp, Bswz);
  pair_gemm<<<NB * MT, 256, 0, stream>>>(Lqp, Rp, Bswz, bg2, Sp);
  final_mlp<<<NB, 256, 0, stream>>>(Sp, Wf1, bf1, Wf2, bf2, out);
}

// Round 5
// 140.071 us; speedup vs baseline: 1.6082x; 1.1071x over previous
//
#include <hip/hip_runtime.h>
#include <hip/hip_bf16.h>

// Problem constants
#define NB   32      // batch
#define NC   24      // image channels
#define ND   12      // spatial
#define NN   144     // ND*ND objects
#define QD   11
#define GH   256
#define FOUT 10
#define MT   324     // m-tiles per batch (20736 pairs / 64)

typedef unsigned short u16;
typedef __attribute__((ext_vector_type(8))) short bf16x8;
typedef __attribute__((ext_vector_type(4))) float f32x4;

// Workspace layout:
//   Lq  f32 [32][144][256]  float-off 0         (= L + q@Wg1_q + bg1 folded in)
//   R   f32 [32][144][256]  float-off 1179648
//   S   f32 [32][256]       float-off 2359296
//   Bswz u16 [128][64][8]   u16-off  4734976    (MFMA B-fragment order)
#define LQ_OFF  0
#define R_OFF   1179648
#define S_OFF   2359296
#define BS_U16  4734976

__device__ inline u16 f2b(float f) {
  __hip_bfloat16 h = __float2bfloat16(f);
  return *reinterpret_cast<u16*>(&h);
}

// ---------------------------------------------------------------------------
// Fused prep:
//  blocks [0, 9216): per-object projections (Lq folds q-term + bg1).
//  blocks [9216, 9472): Wg2 -> bf16 B-fragment swizzle; zero S.
// ---------------------------------------------------------------------------
__global__ __launch_bounds__(256) void prep(const float* __restrict__ image,
                                            const float* __restrict__ question,
                                            const float* __restrict__ Wg1,
                                            const float* __restrict__ bg1,
                                            const float* __restrict__ Wg2,
                                            float* __restrict__ Lq,
                                            float* __restrict__ R,
                                            float* __restrict__ S,
                                            u16* __restrict__ Bswz) {
  int blk = blockIdx.x;
  int h   = threadIdx.x;
  if (blk < 2 * NB * NN) {
    int p     = blk % NN;
    int rest2 = blk / NN;
    int b     = rest2 & (NB - 1);
    int which = rest2 >> 5;
    const float* Wrow = Wg1 + which * (NC + 2) * GH;
    const float* img  = image + b * (NC * NN) + p;
    float acc = 0.f;
#pragma unroll
    for (int c = 0; c < NC; ++c) acc += img[c * NN] * Wrow[c * GH + h];
    int i = p / ND, j = p - i * ND;
    const float inv = 1.0f / (ND - 1);
    acc += (j * inv) * Wrow[24 * GH + h];
    acc += (i * inv) * Wrow[25 * GH + h];
    if (which == 0) {
      acc += bg1[h];
#pragma unroll
      for (int tq = 0; tq < QD; ++tq)
        acc += question[b * QD + tq] * Wg1[(2 * (NC + 2) + tq) * GH + h];
      Lq[(b * NN + p) * GH + h] = acc;
    } else {
      R[(b * NN + p) * GH + h] = acc;
    }
  } else {
    int tid = (blk - 2 * NB * NN) * 256 + h;   // 0..65535
    int e   = tid & 7;
    int l   = (tid >> 3) & 63;
    int fid = tid >> 9;
    int kt  = fid >> 4, nt = fid & 15;
    int k = kt * 32 + ((l >> 4) << 3) + e;
    int n = (nt << 4) + (l & 15);
    Bswz[tid] = f2b(Wg2[k * GH + n]);
    if (tid < NB * GH) S[tid] = 0.f;
  }
}

// ---------------------------------------------------------------------------
// MFMA pair GEMM v5: single-phase. Block = 256 thr (4 waves), tile = 64 pairs
// x 256 cols. XCD-pinned grid (xcd = bid&7 owns batches [4*xcd,4*xcd+4)).
// Phase 1 (build): whole 64x256 A-tile -> LDS in fragment layout (32 KB).
//   thread t: row t>>2, k-octet t&3; per kt: 2x float4 L + 2x float4 R,
//   add+relu+cvt, one ds_write_b128. Write lanes are a permutation of a
//   linear 1KB block -> conflict-free. ONE barrier.
// Phase 2 (mma): per wave 8 kt x {4 ds_read_b128 A, 4 dwordx4 B, 16 MFMA},
//   no barriers, back-to-back MFMA stream. Cross-block overlap (4 blocks/CU)
//   hides build VALU under other blocks' MFMA.
// Epilogue: +bg2, relu, row-sum, shfl-reduce, atomicAdd into S[b,:].
// ---------------------------------------------------------------------------
__global__ __launch_bounds__(256, 4) void pair_gemm(const float* __restrict__ Lq,
                                                    const float* __restrict__ R,
                                                    const u16* __restrict__ Bswz,
                                                    const float* __restrict__ bg2,
                                                    float* __restrict__ S) {
  const int bid   = blockIdx.x;
  const int xcd   = bid & 7;
  const int g     = bid >> 3;            // 0..1295
  const int b     = xcd * 4 + (g / MT);  // batch
  const int mtile = g % MT;
  const int p0    = mtile * 64;
  const int t     = threadIdx.x;
  const int w     = t >> 6;
  const int l     = t & 63;

  // [kt][mf][lane][8] bf16 = 32 KB
  __shared__ __align__(16) u16 As[8 * 4 * 64 * 8];

  // ---- Phase 1: build full A tile ----
  {
    const int brow  = t >> 2;            // 0..63
    const int c     = t & 3;             // k-octet within 32-k step
    const int p     = p0 + brow;
    const int i     = p / NN;
    const int j     = p - i * NN;
    const float* Lrow = Lq + (b * NN + i) * GH + c * 8;
    const float* Rrow = R + (b * NN + j) * GH + c * 8;
    const int lane_w = (brow & 15) | (c << 4);   // lane within fragment
    const int wfrag  = t >> 6;                   // mf = brow>>4 = wave id
    u16* wbase = As + lane_w * 8;
#pragma unroll
    for (int kt = 0; kt < 8; ++kt) {
      float lv[8], rv[8];
      const float* lp = Lrow + kt * 32;
      const float* rp = Rrow + kt * 32;
      *(float4*)&lv[0] = *(const float4*)lp;
      *(float4*)&lv[4] = *(const float4*)(lp + 4);
      *(float4*)&rv[0] = *(const float4*)rp;
      *(float4*)&rv[4] = *(const float4*)(rp + 4);
      u16 o[8];
#pragma unroll
      for (int e = 0; e < 8; ++e) {
        float v = lv[e] + rv[e];
        o[e] = f2b(v > 0.f ? v : 0.f);
      }
      *(bf16x8*)&wbase[((kt << 2) | wfrag) << 9] = *(bf16x8*)o;
    }
  }
  __syncthreads();

  // ---- Phase 2: MFMA stream, no barriers ----
  const u16* Bl = Bswz + l * 8;
  f32x4 acc[4][4] = {};
#pragma unroll
  for (int kt = 0; kt < 8; ++kt) {
    bf16x8 af[4];
#pragma unroll
    for (int mf = 0; mf < 4; ++mf)
      af[mf] = *(const bf16x8*)&As[((((kt << 2) | mf) << 6) | l) << 3];
    bf16x8 bfr[4];
#pragma unroll
    for (int nt = 0; nt < 4; ++nt) {
      int fid = (kt << 4) | (w << 2) | nt;
      bfr[nt] = *(const bf16x8*)(Bl + ((size_t)fid << 9));
    }
#pragma unroll
    for (int mf = 0; mf < 4; ++mf)
#pragma unroll
      for (int nt = 0; nt < 4; ++nt)
        acc[mf][nt] = __builtin_amdgcn_mfma_f32_16x16x32_bf16(
            af[mf], bfr[nt], acc[mf][nt], 0, 0, 0);
  }

  // Epilogue: C/D layout col = l&15, row = (l>>4)*4 + reg.
  float* Sb = S + b * GH;
#pragma unroll
  for (int nt = 0; nt < 4; ++nt) {
    int n = (w << 6) + (nt << 4) + (l & 15);
    float bgv = bg2[n];
    float s = 0.f;
#pragma unroll
    for (int mf = 0; mf < 4; ++mf)
#pragma unroll
      for (int r = 0; r < 4; ++r) {
        float v = acc[mf][nt][r] + bgv;
        s += v > 0.f ? v : 0.f;
      }
    s += __shfl_xor(s, 16, 64);
    s += __shfl_xor(s, 32, 64);
    if ((l >> 4) == 0) atomicAdd(&Sb[n], s);
  }
}

// ---------------------------------------------------------------------------
// Final f-MLP: out = relu(S@Wf1+bf1)@Wf2+bf2. One block per batch.
// ---------------------------------------------------------------------------
__global__ __launch_bounds__(256) void final_mlp(const float* __restrict__ S,
                                                 const float* __restrict__ Wf1,
                                                 const float* __restrict__ bf1,
                                                 const float* __restrict__ Wf2,
                                                 const float* __restrict__ bf2,
                                                 float* __restrict__ out) {
  __shared__ float sS[GH];
  __shared__ float oS[GH];
  int b = blockIdx.x, h = threadIdx.x;
  sS[h] = S[b * GH + h];
  __syncthreads();
  float acc = bf1[h];
#pragma unroll 8
  for (int k = 0; k < GH; ++k) acc += sS[k] * Wf1[k * GH + h];
  oS[h] = acc > 0.f ? acc : 0.f;
  __syncthreads();
  if (h < FOUT) {
    float o = bf2[h];
#pragma unroll 8
    for (int k = 0; k < GH; ++k) o += oS[k] * Wf2[k * FOUT + h];
    out[b * FOUT + h] = o;
  }
}

extern "C" void kernel_launch(void* const* d_in, const int* in_sizes, int n_in,
                              void* d_out, int out_size, void* d_ws, size_t ws_size,
                              hipStream_t stream) {
  const float* image    = (const float*)d_in[0];
  const float* question = (const float*)d_in[1];
  const float* Wg1      = (const float*)d_in[2];
  const float* bg1      = (const float*)d_in[3];
  const float* Wg2      = (const float*)d_in[4];
  const float* bg2      = (const float*)d_in[5];
  const float* Wf1      = (const float*)d_in[6];
  const float* bf1      = (const float*)d_in[7];
  const float* Wf2      = (const float*)d_in[8];
  const float* bf2      = (const float*)d_in[9];
  float* out = (float*)d_out;

  float* wsf  = (float*)d_ws;
  float* Lqp  = wsf + LQ_OFF;
  float* Rp   = wsf + R_OFF;
  float* Sp   = wsf + S_OFF;
  u16*   Bswz = (u16*)d_ws + BS_U16;

  prep<<<2 * NB * NN + 256, 256, 0, stream>>>(image, question, Wg1, bg1, Wg2,
                                              Lqp, Rp, Sp, Bswz);
  pair_gemm<<<NB * MT, 256, 0, stream>>>(Lqp, Rp, Bswz, bg2, Sp);
  final_mlp<<<NB, 256, 0, stream>>>(Sp, Wf1, bf1, Wf2, bf2, out);
}